// Round 16
// baseline (150.757 us; speedup 1.0000x reference)
//
#include <hip/hip_runtime.h>

#define D 4096

typedef float fx4 __attribute__((ext_vector_type(4)));

// ws layout (floats):
//   CS0=0 colsum0[D] (atomics; memset)   CS1=D colsum1[D] (atomics; memset)
//   RS1=2D rowsum1[D] (by applyT1)       RS2=3D rowsum2[D] (by applyT2)
//   M0=4D M1=5D M2=6D M3=7D  messages    S2S=8D  S2 scalar
#define CS0 0
#define CS1 D
#define RS1 (2 * D)
#define RS2 (3 * D)
#define M0O (4 * D)
#define M1O (5 * D)
#define M2O (6 * D)
#define M3O (7 * D)
#define S2S (8 * D)

// ---------------- K1: colsums of t0,t1 (R10-proven) ----------------
__global__ void __launch_bounds__(256) colsum_kernel(
        const float* __restrict__ t0, const float* __restrict__ t1,
        float* __restrict__ ws) {
    int b = blockIdx.x;
    const float* A = (b < 256) ? t0 : t1;
    float* out = ws + ((b < 256) ? CS0 : CS1);
    int lb = b & 255;
    int c4 = (lb & 3) * 256 + threadIdx.x;     // fx4-column 0..1023
    int r0 = (lb >> 2) * 64;                   // 64-row stripe
    const fx4* A4 = (const fx4*)A;
    fx4 s = (fx4){0.f, 0.f, 0.f, 0.f};
    #pragma unroll 8
    for (int r = 0; r < 64; ++r)
        s += A4[(size_t)(r0 + r) * (D / 4) + c4];
    atomicAdd(&out[c4 * 4 + 0], s.x);
    atomicAdd(&out[c4 * 4 + 1], s.y);
    atomicAdd(&out[c4 * 4 + 2], s.z);
    atomicAdd(&out[c4 * 4 + 3], s.w);
}

// ---------------- single-block message kernels (R10-proven bodies) ----------------

__device__ __forceinline__ float block_sum_1024(float v, float* red) {
    #pragma unroll
    for (int o = 32; o > 0; o >>= 1) v += __shfl_down(v, o);
    int lane = threadIdx.x & 63, wid = threadIdx.x >> 6;
    if (lane == 0) red[wid] = v;
    __syncthreads();
    if (threadIdx.x == 0) {
        float t = 0.f;
        #pragma unroll
        for (int w = 0; w < 16; ++w) t += red[w];
        red[0] = t;
    }
    __syncthreads();
    float r = red[0];
    __syncthreads();
    return r;
}

// msgsA: m0 = remap(CS0, op0); S0 = sum(m0); m1 = remap(CS1 + S0, op1)
__global__ void __launch_bounds__(1024) msgsA_kernel(
        float* __restrict__ ws, const int* __restrict__ op0,
        const int* __restrict__ op1) {
    __shared__ float m0[D], m1[D];
    __shared__ float red[16];
    int tid = threadIdx.x;

    int s0[4], d0[4], s1[4], d1[4];
    #pragma unroll
    for (int k = 0; k < 4; ++k) {
        int i = tid + k * 1024;
        s0[k] = op0[i]; d0[k] = op0[D + i];
        s1[k] = op1[i]; d1[k] = op1[D + i];
    }
    float g0[4], g1[4];
    #pragma unroll
    for (int k = 0; k < 4; ++k) {
        g0[k] = ws[CS0 + s0[k]];
        g1[k] = ws[CS1 + s1[k]];
    }
    #pragma unroll
    for (int k = 0; k < 4; ++k) {
        int i = tid + k * 1024;
        m0[i] = 0.f; m1[i] = 0.f;
    }
    __syncthreads();
    #pragma unroll
    for (int k = 0; k < 4; ++k) atomicAdd(&m0[d0[k]], g0[k]);
    __syncthreads();
    float p = 0.f;
    #pragma unroll
    for (int k = 0; k < 4; ++k) p += m0[tid + k * 1024];
    float S0 = block_sum_1024(p, red);
    #pragma unroll
    for (int k = 0; k < 4; ++k) atomicAdd(&m1[d1[k]], g1[k] + S0);
    __syncthreads();
    #pragma unroll
    for (int k = 0; k < 4; ++k) {
        int i = tid + k * 1024;
        ws[M0O + i] = m0[i];
        ws[M1O + i] = m1[i];
    }
}

// msgsB: m2 = remap(RS2 + 4095*m1, op2); S2 = sum(m2)
__global__ void __launch_bounds__(1024) msgsB_kernel(
        float* __restrict__ ws, const int* __restrict__ op2) {
    __shared__ float m2[D];
    __shared__ float red[16];
    int tid = threadIdx.x;

    int s2[4], d2[4];
    #pragma unroll
    for (int k = 0; k < 4; ++k) {
        int i = tid + k * 1024;
        s2[k] = op2[i]; d2[k] = op2[D + i];
    }
    float g2[4];
    #pragma unroll
    for (int k = 0; k < 4; ++k)
        g2[k] = ws[RS2 + s2[k]] + 4095.0f * ws[M1O + s2[k]];
    #pragma unroll
    for (int k = 0; k < 4; ++k) m2[tid + k * 1024] = 0.f;
    __syncthreads();
    #pragma unroll
    for (int k = 0; k < 4; ++k) atomicAdd(&m2[d2[k]], g2[k]);
    __syncthreads();
    float p = 0.f;
    #pragma unroll
    for (int k = 0; k < 4; ++k) p += m2[tid + k * 1024];
    float S2 = block_sum_1024(p, red);
    #pragma unroll
    for (int k = 0; k < 4; ++k) {
        int i = tid + k * 1024;
        ws[M2O + i] = m2[i];
    }
    if (tid == 0) ws[S2S] = S2;
}

// msgsC: m3 = remap(RS1 + 4095*m0 + S2, op3)
__global__ void __launch_bounds__(1024) msgsC_kernel(
        float* __restrict__ ws, const int* __restrict__ op3) {
    __shared__ float m3[D];
    int tid = threadIdx.x;

    int s3[4], d3[4];
    #pragma unroll
    for (int k = 0; k < 4; ++k) {
        int i = tid + k * 1024;
        s3[k] = op3[i]; d3[k] = op3[D + i];
    }
    float S2 = ws[S2S];
    float g3[4];
    #pragma unroll
    for (int k = 0; k < 4; ++k)
        g3[k] = ws[RS1 + s3[k]] + 4095.0f * ws[M0O + s3[k]] + S2;
    #pragma unroll
    for (int k = 0; k < 4; ++k) m3[tid + k * 1024] = 0.f;
    __syncthreads();
    #pragma unroll
    for (int k = 0; k < 4; ++k) atomicAdd(&m3[d3[k]], g3[k]);
    __syncthreads();
    #pragma unroll
    for (int k = 0; k < 4; ++k) {
        int i = tid + k * 1024;
        ws[M3O + i] = m3[i];
    }
}

// ---------------- apply kernels (R10 bodies, PLAIN stores) ----------------

__device__ __forceinline__ void row_reduce_store(float s, float* dst) {
    __shared__ float red[4];
    #pragma unroll
    for (int o = 32; o > 0; o >>= 1) s += __shfl_down(s, o);
    int lane = threadIdx.x & 63, wid = threadIdx.x >> 6;
    if (lane == 0) red[wid] = s;
    __syncthreads();
    if (threadIdx.x == 0) *dst = (red[0] + red[1]) + (red[2] + red[3]);
}

// out2 = t2 + m1[row]; RS2[row] = rowsum(t2 row)
__global__ void __launch_bounds__(256) applyT2_kernel(
        const float* __restrict__ t2, float* __restrict__ ws,
        float* __restrict__ out2) {
    int row = blockIdx.x;
    size_t base = (size_t)row * D;
    const fx4* src = (const fx4*)(t2 + base);
    fx4* dst = (fx4*)(out2 + base);
    float rr = ws[M1O + row];

    fx4 v[4];
    float s = 0.f;
    #pragma unroll
    for (int k = 0; k < 4; ++k) {
        v[k] = src[threadIdx.x + 256 * k];
        s += (v[k].x + v[k].y) + (v[k].z + v[k].w);
    }
    #pragma unroll
    for (int k = 0; k < 4; ++k)
        dst[threadIdx.x + 256 * k] = v[k] + rr;
    row_reduce_store(s, ws + RS2 + row);
}

// out1 = t1 + m0[row] + m2[col]; RS1[row] = rowsum(t1 row)
__global__ void __launch_bounds__(256) applyT1_kernel(
        const float* __restrict__ t1, float* __restrict__ ws,
        float* __restrict__ out1) {
    int row = blockIdx.x;
    size_t base = (size_t)row * D;
    const fx4* src = (const fx4*)(t1 + base);
    const fx4* c4 = (const fx4*)(ws + M2O);
    fx4* dst = (fx4*)(out1 + base);
    float rr = ws[M0O + row];

    fx4 v[4], c[4];
    float s = 0.f;
    #pragma unroll
    for (int k = 0; k < 4; ++k) {
        v[k] = src[threadIdx.x + 256 * k];
        c[k] = c4[threadIdx.x + 256 * k];
        s += (v[k].x + v[k].y) + (v[k].z + v[k].w);
    }
    #pragma unroll
    for (int k = 0; k < 4; ++k)
        dst[threadIdx.x + 256 * k] = v[k] + c[k] + rr;
    row_reduce_store(s, ws + RS1 + row);
}

// out0 = t0 + m3[col]
__global__ void __launch_bounds__(256) applyT0_kernel(
        const float* __restrict__ t0, const float* __restrict__ ws,
        float* __restrict__ out0) {
    int row = blockIdx.x;
    size_t base = (size_t)row * D;
    const fx4* src = (const fx4*)(t0 + base);
    const fx4* c4 = (const fx4*)(ws + M3O);
    fx4* dst = (fx4*)(out0 + base);

    #pragma unroll
    for (int k = 0; k < 4; ++k)
        dst[threadIdx.x + 256 * k] = src[threadIdx.x + 256 * k]
                                   + c4[threadIdx.x + 256 * k];
}

extern "C" void kernel_launch(void* const* d_in, const int* in_sizes, int n_in,
                              void* d_out, int out_size, void* d_ws, size_t ws_size,
                              hipStream_t stream) {
    const float* t0 = (const float*)d_in[0];
    const float* t1 = (const float*)d_in[1];
    const float* t2 = (const float*)d_in[2];
    const int* op0 = (const int*)d_in[3];
    const int* op1 = (const int*)d_in[4];
    const int* op2 = (const int*)d_in[5];
    const int* op3 = (const int*)d_in[6];
    float* out = (float*)d_out;
    float* ws = (float*)d_ws;

    hipMemsetAsync(ws, 0, 2 * D * sizeof(float), stream);     // CS0, CS1

    colsum_kernel<<<512, 256, 0, stream>>>(t0, t1, ws);
    msgsA_kernel<<<1, 1024, 0, stream>>>(ws, op0, op1);
    applyT2_kernel<<<D, 256, 0, stream>>>(t2, ws, out + 2 * (size_t)D * D);
    msgsB_kernel<<<1, 1024, 0, stream>>>(ws, op2);
    applyT1_kernel<<<D, 256, 0, stream>>>(t1, ws, out + 1 * (size_t)D * D);
    msgsC_kernel<<<1, 1024, 0, stream>>>(ws, op3);
    applyT0_kernel<<<D, 256, 0, stream>>>(t0, ws, out + 0 * (size_t)D * D);
}

// Round 17
// 134.859 us; speedup vs baseline: 1.1179x; 1.1179x over previous
//
#include <hip/hip_runtime.h>

#define D 4096

typedef float fx4 __attribute__((ext_vector_type(4)));

// ws layout (floats):
//   CS0=0 colsum0[D] (atomics; memset)   CS1=D colsum1[D] (atomics; memset)
//   RS1=2D rowsum1[D] (by applyT1)       RS2=3D rowsum2[D] (by applyT2)
//   M0=4D M1=5D M2=6D M3=7D  messages    S2S=8D  S2 scalar
#define CS0 0
#define CS1 D
#define RS1 (2 * D)
#define RS2 (3 * D)
#define M0O (4 * D)
#define M1O (5 * D)
#define M2O (6 * D)
#define M3O (7 * D)
#define S2S (8 * D)

// ---------------- K1: colsums of t0,t1 ----------------
// 512 blocks x 256: [0,256) t0 -> CS0, [256,512) t1 -> CS1. 64-way/addr atomics.
__global__ void __launch_bounds__(256) colsum_kernel(
        const float* __restrict__ t0, const float* __restrict__ t1,
        float* __restrict__ ws) {
    int b = blockIdx.x;
    const float* A = (b < 256) ? t0 : t1;
    float* out = ws + ((b < 256) ? CS0 : CS1);
    int lb = b & 255;
    int c4 = (lb & 3) * 256 + threadIdx.x;     // fx4-column 0..1023
    int r0 = (lb >> 2) * 64;                   // 64-row stripe
    const fx4* A4 = (const fx4*)A;
    fx4 s = (fx4){0.f, 0.f, 0.f, 0.f};
    #pragma unroll 8
    for (int r = 0; r < 64; ++r)
        s += A4[(size_t)(r0 + r) * (D / 4) + c4];
    atomicAdd(&out[c4 * 4 + 0], s.x);
    atomicAdd(&out[c4 * 4 + 1], s.y);
    atomicAdd(&out[c4 * 4 + 2], s.z);
    atomicAdd(&out[c4 * 4 + 3], s.w);
}

// ---------------- single-block message kernels ----------------

__device__ __forceinline__ float block_sum_1024(float v, float* red) {
    #pragma unroll
    for (int o = 32; o > 0; o >>= 1) v += __shfl_down(v, o);
    int lane = threadIdx.x & 63, wid = threadIdx.x >> 6;
    if (lane == 0) red[wid] = v;
    __syncthreads();
    if (threadIdx.x == 0) {
        float t = 0.f;
        #pragma unroll
        for (int w = 0; w < 16; ++w) t += red[w];
        red[0] = t;
    }
    __syncthreads();
    float r = red[0];
    __syncthreads();
    return r;
}

// msgsA: m0 = remap(CS0, op0); S0 = sum(m0); m1 = remap(CS1 + S0, op1)
__global__ void __launch_bounds__(1024) msgsA_kernel(
        float* __restrict__ ws, const int* __restrict__ op0,
        const int* __restrict__ op1) {
    __shared__ float m0[D], m1[D];
    __shared__ float red[16];
    int tid = threadIdx.x;

    int s0[4], d0[4], s1[4], d1[4];
    #pragma unroll
    for (int k = 0; k < 4; ++k) {
        int i = tid + k * 1024;
        s0[k] = op0[i]; d0[k] = op0[D + i];
        s1[k] = op1[i]; d1[k] = op1[D + i];
    }
    float g0[4], g1[4];
    #pragma unroll
    for (int k = 0; k < 4; ++k) {
        g0[k] = ws[CS0 + s0[k]];
        g1[k] = ws[CS1 + s1[k]];
    }
    #pragma unroll
    for (int k = 0; k < 4; ++k) {
        int i = tid + k * 1024;
        m0[i] = 0.f; m1[i] = 0.f;
    }
    __syncthreads();
    #pragma unroll
    for (int k = 0; k < 4; ++k) atomicAdd(&m0[d0[k]], g0[k]);
    __syncthreads();
    float p = 0.f;
    #pragma unroll
    for (int k = 0; k < 4; ++k) p += m0[tid + k * 1024];
    float S0 = block_sum_1024(p, red);
    #pragma unroll
    for (int k = 0; k < 4; ++k) atomicAdd(&m1[d1[k]], g1[k] + S0);
    __syncthreads();
    #pragma unroll
    for (int k = 0; k < 4; ++k) {
        int i = tid + k * 1024;
        ws[M0O + i] = m0[i];
        ws[M1O + i] = m1[i];
    }
}

// msgsB: m2 = remap(RS2 + 4095*m1, op2); S2 = sum(m2)
__global__ void __launch_bounds__(1024) msgsB_kernel(
        float* __restrict__ ws, const int* __restrict__ op2) {
    __shared__ float m2[D];
    __shared__ float red[16];
    int tid = threadIdx.x;

    int s2[4], d2[4];
    #pragma unroll
    for (int k = 0; k < 4; ++k) {
        int i = tid + k * 1024;
        s2[k] = op2[i]; d2[k] = op2[D + i];
    }
    float g2[4];
    #pragma unroll
    for (int k = 0; k < 4; ++k)
        g2[k] = ws[RS2 + s2[k]] + 4095.0f * ws[M1O + s2[k]];
    #pragma unroll
    for (int k = 0; k < 4; ++k) m2[tid + k * 1024] = 0.f;
    __syncthreads();
    #pragma unroll
    for (int k = 0; k < 4; ++k) atomicAdd(&m2[d2[k]], g2[k]);
    __syncthreads();
    float p = 0.f;
    #pragma unroll
    for (int k = 0; k < 4; ++k) p += m2[tid + k * 1024];
    float S2 = block_sum_1024(p, red);
    #pragma unroll
    for (int k = 0; k < 4; ++k) {
        int i = tid + k * 1024;
        ws[M2O + i] = m2[i];
    }
    if (tid == 0) ws[S2S] = S2;
}

// msgsC: m3 = remap(RS1 + 4095*m0 + S2, op3)
__global__ void __launch_bounds__(1024) msgsC_kernel(
        float* __restrict__ ws, const int* __restrict__ op3) {
    __shared__ float m3[D];
    int tid = threadIdx.x;

    int s3[4], d3[4];
    #pragma unroll
    for (int k = 0; k < 4; ++k) {
        int i = tid + k * 1024;
        s3[k] = op3[i]; d3[k] = op3[D + i];
    }
    float S2 = ws[S2S];
    float g3[4];
    #pragma unroll
    for (int k = 0; k < 4; ++k)
        g3[k] = ws[RS1 + s3[k]] + 4095.0f * ws[M0O + s3[k]] + S2;
    #pragma unroll
    for (int k = 0; k < 4; ++k) m3[tid + k * 1024] = 0.f;
    __syncthreads();
    #pragma unroll
    for (int k = 0; k < 4; ++k) atomicAdd(&m3[d3[k]], g3[k]);
    __syncthreads();
    #pragma unroll
    for (int k = 0; k < 4; ++k) {
        int i = tid + k * 1024;
        ws[M3O + i] = m3[i];
    }
}

// ---------------- apply kernels (1 row per 256-thread block; nt stores) ----------------

__device__ __forceinline__ void row_reduce_store(float s, float* dst) {
    __shared__ float red[4];
    #pragma unroll
    for (int o = 32; o > 0; o >>= 1) s += __shfl_down(s, o);
    int lane = threadIdx.x & 63, wid = threadIdx.x >> 6;
    if (lane == 0) red[wid] = s;
    __syncthreads();
    if (threadIdx.x == 0) *dst = (red[0] + red[1]) + (red[2] + red[3]);
}

// out2 = t2 + m1[row]; RS2[row] = rowsum(t2 row)
__global__ void __launch_bounds__(256) applyT2_kernel(
        const float* __restrict__ t2, float* __restrict__ ws,
        float* __restrict__ out2) {
    int row = blockIdx.x;
    size_t base = (size_t)row * D;
    const fx4* src = (const fx4*)(t2 + base);
    fx4* dst = (fx4*)(out2 + base);
    float rr = ws[M1O + row];

    fx4 v[4];
    float s = 0.f;
    #pragma unroll
    for (int k = 0; k < 4; ++k) {
        v[k] = src[threadIdx.x + 256 * k];
        s += (v[k].x + v[k].y) + (v[k].z + v[k].w);
    }
    #pragma unroll
    for (int k = 0; k < 4; ++k)
        __builtin_nontemporal_store(v[k] + rr, &dst[threadIdx.x + 256 * k]);
    row_reduce_store(s, ws + RS2 + row);
}

// out1 = t1 + m0[row] + m2[col]; RS1[row] = rowsum(t1 row)
__global__ void __launch_bounds__(256) applyT1_kernel(
        const float* __restrict__ t1, float* __restrict__ ws,
        float* __restrict__ out1) {
    int row = blockIdx.x;
    size_t base = (size_t)row * D;
    const fx4* src = (const fx4*)(t1 + base);
    const fx4* c4 = (const fx4*)(ws + M2O);
    fx4* dst = (fx4*)(out1 + base);
    float rr = ws[M0O + row];

    fx4 v[4], c[4];
    float s = 0.f;
    #pragma unroll
    for (int k = 0; k < 4; ++k) {
        v[k] = src[threadIdx.x + 256 * k];
        c[k] = c4[threadIdx.x + 256 * k];
        s += (v[k].x + v[k].y) + (v[k].z + v[k].w);
    }
    #pragma unroll
    for (int k = 0; k < 4; ++k)
        __builtin_nontemporal_store(v[k] + c[k] + rr,
                                    &dst[threadIdx.x + 256 * k]);
    row_reduce_store(s, ws + RS1 + row);
}

// out0 = t0 + m3[col]
__global__ void __launch_bounds__(256) applyT0_kernel(
        const float* __restrict__ t0, const float* __restrict__ ws,
        float* __restrict__ out0) {
    int row = blockIdx.x;
    size_t base = (size_t)row * D;
    const fx4* src = (const fx4*)(t0 + base);
    const fx4* c4 = (const fx4*)(ws + M3O);
    fx4* dst = (fx4*)(out0 + base);

    #pragma unroll
    for (int k = 0; k < 4; ++k) {
        fx4 r = src[threadIdx.x + 256 * k] + c4[threadIdx.x + 256 * k];
        __builtin_nontemporal_store(r, &dst[threadIdx.x + 256 * k]);
    }
}

extern "C" void kernel_launch(void* const* d_in, const int* in_sizes, int n_in,
                              void* d_out, int out_size, void* d_ws, size_t ws_size,
                              hipStream_t stream) {
    const float* t0 = (const float*)d_in[0];
    const float* t1 = (const float*)d_in[1];
    const float* t2 = (const float*)d_in[2];
    const int* op0 = (const int*)d_in[3];
    const int* op1 = (const int*)d_in[4];
    const int* op2 = (const int*)d_in[5];
    const int* op3 = (const int*)d_in[6];
    float* out = (float*)d_out;
    float* ws = (float*)d_ws;

    hipMemsetAsync(ws, 0, 2 * D * sizeof(float), stream);     // CS0, CS1

    colsum_kernel<<<512, 256, 0, stream>>>(t0, t1, ws);
    msgsA_kernel<<<1, 1024, 0, stream>>>(ws, op0, op1);       // m0, m1
    applyT2_kernel<<<D, 256, 0, stream>>>(t2, ws, out + 2 * (size_t)D * D);  // +RS2
    msgsB_kernel<<<1, 1024, 0, stream>>>(ws, op2);            // m2, S2
    applyT1_kernel<<<D, 256, 0, stream>>>(t1, ws, out + 1 * (size_t)D * D);  // +RS1
    msgsC_kernel<<<1, 1024, 0, stream>>>(ws, op3);            // m3
    applyT0_kernel<<<D, 256, 0, stream>>>(t0, ws, out + 0 * (size_t)D * D);
}